// Round 5
// baseline (107.990 us; speedup 1.0000x reference)
//
#include <hip/hip_runtime.h>
#include <math.h>

#define N_SPK 512
#define N_UTT 32
#define DIM   512
#define EPSN  1e-8f

typedef __attribute__((ext_vector_type(8))) short  short8;  // 8 bf16 = 4 VGPR
typedef __attribute__((ext_vector_type(4))) float  f32x4;   // MFMA C/D

// fp32 -> bf16 round-to-nearest-even
__device__ inline unsigned short f2bf(float x) {
  unsigned int u = __builtin_bit_cast(unsigned int, x);
  unsigned int r = (u + 0x7fffu + ((u >> 16) & 1u)) >> 16;
  return (unsigned short)r;
}

// ws: [0,512KB) cnk bf16 K-chunked cnk[(kc*N_SPK+c)*32+(k&31)];
//     [512KB, +2KB) partials; then a 4B done-counter.
#define CNK_ELEMS (N_SPK * DIM)

// Kernel 1: centroid (mean over U) + fp32 L2-normalize -> bf16 K-chunked cnk.
// (Unchanged from R3 — passed.) Also zeroes the done-counter used by the
// ge2e kernel's fused last-block finalize (stream order makes it visible).
__global__ __launch_bounds__(256) void centroid_kernel(
    const float* __restrict__ emb, unsigned short* __restrict__ cnk,
    unsigned int* __restrict__ counter) {
  int j = blockIdx.x, t = threadIdx.x;
  if (j == 0 && t == 0) *counter = 0;
  int c4 = t & 127, half = t >> 7;  // c4: which float4 of the row (128/row)
  const float4* base = (const float4*)(emb + (size_t)j * N_UTT * DIM);
  float4 s = {0.f, 0.f, 0.f, 0.f};
#pragma unroll
  for (int u = 0; u < 16; ++u) {
    float4 v = base[(half + 2 * u) * 128 + c4];
    s.x += v.x; s.y += v.y; s.z += v.z; s.w += v.w;
  }
  __shared__ float4 comb[128];
  if (half) comb[c4] = s;
  __syncthreads();
  float4 m = {0.f, 0.f, 0.f, 0.f};
  float ss = 0.f;
  if (!half) {
    float4 o = comb[c4];
    m.x = (s.x + o.x) * (1.f / N_UTT);
    m.y = (s.y + o.y) * (1.f / N_UTT);
    m.z = (s.z + o.z) * (1.f / N_UTT);
    m.w = (s.w + o.w) * (1.f / N_UTT);
    ss = m.x * m.x + m.y * m.y + m.z * m.z + m.w * m.w;
  }
#pragma unroll
  for (int off = 32; off > 0; off >>= 1) ss += __shfl_xor(ss, off, 64);
  __shared__ float red[4];
  if ((t & 63) == 0) red[t >> 6] = ss;
  __syncthreads();
  float total = red[0] + red[1] + red[2] + red[3];
  float inv = 1.f / fmaxf(sqrtf(total), EPSN);
  if (!half) {
    int d0 = c4 * 4;
    int kc = d0 >> 5;
    unsigned short* p = cnk + ((size_t)kc * N_SPK + j) * 32 + (d0 & 31);
    p[0] = f2bf(m.x * inv); p[1] = f2bf(m.y * inv);
    p[2] = f2bf(m.z * inv); p[3] = f2bf(m.w * inv);
  }
}

// Kernel 2: block j = speaker j, 1024 threads (16 waves; wave owns 32 cols).
// 512 blocks x 16 waves = 32 waves/CU = 8 waves/SIMD — 2x R3's latency
// hiding for the L2-hot B loads (the R3 kernel was latency-bound at 4/SIMD).
// E tile XOR-swizzled in LDS as before. Fused last-block finalize.
__global__ __launch_bounds__(1024, 8) void ge2e_kernel(
    const float* __restrict__ emb, const unsigned short* __restrict__ cnk,
    const float* __restrict__ wp, const float* __restrict__ bp,
    float* __restrict__ partials, unsigned int* __restrict__ counter,
    float* __restrict__ out) {
  __shared__ __align__(16) unsigned short E[N_UTT * DIM];  // 32 KB
  __shared__ float red[16][N_UTT][2];                      // 4 KB (m, s)
  __shared__ float dred[16];
  __shared__ float nred[16];
  __shared__ int amLast;

  int j = blockIdx.x;
  int t = threadIdx.x;
  int lane = t & 63, wid = t >> 6;          // wid 0..15
  int n15 = lane & 15, quad = lane >> 4;

  // ---- stage + fp32 normalize + bf16 pack; wave wid owns rows wid*2.. ----
#pragma unroll
  for (int r8 = 0; r8 < 2; ++r8) {
    int r = wid * 2 + r8;
    const float* rp = emb + ((size_t)j * N_UTT + r) * DIM + lane * 8;
    float4 v0 = *(const float4*)rp;
    float4 v1 = *(const float4*)(rp + 4);
    float ss = v0.x * v0.x + v0.y * v0.y + v0.z * v0.z + v0.w * v0.w +
               v1.x * v1.x + v1.y * v1.y + v1.z * v1.z + v1.w * v1.w;
#pragma unroll
    for (int off = 32; off > 0; off >>= 1) ss += __shfl_xor(ss, off, 64);
    float inv = 1.f / fmaxf(sqrtf(ss), EPSN);
    short8 pk;
    pk[0] = (short)f2bf(v0.x * inv); pk[1] = (short)f2bf(v0.y * inv);
    pk[2] = (short)f2bf(v0.z * inv); pk[3] = (short)f2bf(v0.w * inv);
    pk[4] = (short)f2bf(v1.x * inv); pk[5] = (short)f2bf(v1.y * inv);
    pk[6] = (short)f2bf(v1.z * inv); pk[7] = (short)f2bf(v1.w * inv);
    int sw = lane ^ (r & 7);  // 16B-chunk XOR swizzle
    *(short8*)&E[r * DIM + sw * 8] = pk;
  }
  __syncthreads();

  // ---- MFMA GEMM: wave wid computes rows 0..31 x cols wid*32..+31 ----
  f32x4 acc[2][2];
#pragma unroll
  for (int mt = 0; mt < 2; ++mt)
#pragma unroll
    for (int nt = 0; nt < 2; ++nt) acc[mt][nt] = (f32x4){0.f, 0.f, 0.f, 0.f};

#pragma unroll 4
  for (int ks = 0; ks < 16; ++ks) {
    short8 b[2];
#pragma unroll
    for (int nt = 0; nt < 2; ++nt) {
      int c = wid * 32 + nt * 16 + n15;  // B[n][k]: contiguous 1KB per run
      b[nt] = *(const short8*)(cnk + ((size_t)ks * N_SPK + c) * 32 + quad * 8);
    }
    short8 a[2];
#pragma unroll
    for (int mt = 0; mt < 2; ++mt) {
      int r = mt * 16 + n15;
      int sw = (ks * 4 + quad) ^ (r & 7);
      a[mt] = *(const short8*)&E[r * DIM + sw * 8];
    }
#pragma unroll
    for (int mt = 0; mt < 2; ++mt)
#pragma unroll
      for (int nt = 0; nt < 2; ++nt)
        acc[mt][nt] = __builtin_amdgcn_mfma_f32_16x16x32_bf16(
            a[mt], b[nt], acc[mt][nt], 0, 0, 0);
  }

  // ---- epilogue: logits = w*sim+b, fused LSE + diag ----
  float w = *wp, bb = *bp;
  float dsum = 0.f;
#pragma unroll
  for (int mt = 0; mt < 2; ++mt)
#pragma unroll
    for (int nt = 0; nt < 2; ++nt) {
      int c = wid * 32 + nt * 16 + n15;
      bool isdiag = (c == j);
#pragma unroll
      for (int rg = 0; rg < 4; ++rg) {
        float v = fmaf(w, acc[mt][nt][rg], bb);
        acc[mt][nt][rg] = v;
        if (isdiag) dsum += v;
      }
    }

#pragma unroll
  for (int mt = 0; mt < 2; ++mt)
#pragma unroll
    for (int rg = 0; rg < 4; ++rg) {
      float m = -INFINITY;
#pragma unroll
      for (int nt = 0; nt < 2; ++nt) m = fmaxf(m, acc[mt][nt][rg]);
#pragma unroll
      for (int off = 1; off < 16; off <<= 1) m = fmaxf(m, __shfl_xor(m, off, 64));
      float s = 0.f;
#pragma unroll
      for (int nt = 0; nt < 2; ++nt) s += __expf(acc[mt][nt][rg] - m);
#pragma unroll
      for (int off = 1; off < 16; off <<= 1) s += __shfl_xor(s, off, 64);
      if (n15 == 0) {
        int r = mt * 16 + quad * 4 + rg;
        red[wid][r][0] = m;
        red[wid][r][1] = s;
      }
    }
#pragma unroll
  for (int off = 32; off > 0; off >>= 1) dsum += __shfl_xor(dsum, off, 64);
  if (lane == 0) dred[wid] = dsum;
  __syncthreads();

  // combine 16 wave-partials per row; rows 0..31 on threads 0..31
  if (t < 32) {
    float M = -INFINITY;
#pragma unroll
    for (int ww = 0; ww < 16; ++ww) M = fmaxf(M, red[ww][t][0]);
    float S = 0.f;
#pragma unroll
    for (int ww = 0; ww < 16; ++ww)
      S += red[ww][t][1] * __expf(red[ww][t][0] - M);
    float lse = M + __logf(S);
#pragma unroll
    for (int off = 16; off > 0; off >>= 1) lse += __shfl_xor(lse, off, 64);
    if (t == 0) {
      float d = 0.f;
#pragma unroll
      for (int ww = 0; ww < 16; ++ww) d += dred[ww];
      partials[j] = lse - d;
    }
  }

  // ---- fused finalize: last block to arrive reduces the 512 partials ----
  if (t == 0) {
    __threadfence();                       // release partials[j] device-wide
    unsigned int old = atomicAdd(counter, 1u);
    amLast = (old == (unsigned int)(gridDim.x - 1));
  }
  __syncthreads();
  if (amLast) {
    __threadfence();                       // acquire all partials
    float v = (t < N_SPK) ? partials[t] : 0.f;
#pragma unroll
    for (int off = 32; off > 0; off >>= 1) v += __shfl_xor(v, off, 64);
    if (lane == 0) nred[wid] = v;
    __syncthreads();
    if (t == 0) {
      float s = 0.f;
#pragma unroll
      for (int ww = 0; ww < 16; ++ww) s += nred[ww];
      out[0] = s * (1.f / (N_SPK * N_UTT));
    }
  }
}

extern "C" void kernel_launch(void* const* d_in, const int* in_sizes, int n_in,
                              void* d_out, int out_size, void* d_ws, size_t ws_size,
                              hipStream_t stream) {
  const float* emb = (const float*)d_in[0];
  const float* wp  = (const float*)d_in[1];
  const float* bp  = (const float*)d_in[2];
  float* out = (float*)d_out;
  unsigned short* cnk = (unsigned short*)d_ws;                      // 512 KB
  float* partials = (float*)((char*)d_ws + (size_t)CNK_ELEMS * 2);  // 2 KB
  unsigned int* counter =
      (unsigned int*)((char*)d_ws + (size_t)CNK_ELEMS * 2 + N_SPK * 4);

  centroid_kernel<<<N_SPK, 256, 0, stream>>>(emb, cnk, counter);
  ge2e_kernel<<<N_SPK, 1024, 0, stream>>>(emb, cnk, wp, bp, partials, counter,
                                          out);
}